// Round 1
// baseline (96.205 us; speedup 1.0000x reference)
//
#include <hip/hip_runtime.h>
#include <math.h>

#define B_N 8192
#define U_N 256
#define F_N 128
#define UB  16   // u's per block

// Prep: A[u,f] = 1/sa^2 ; B2[u,f] = 2*s/sa^2 ; C[u] = sum_f s^2/sa^2
__global__ __launch_bounds__(64) void prep_kernel(
    const float* __restrict__ shift, const float* __restrict__ semi,
    float* __restrict__ A, float* __restrict__ B2, float* __restrict__ C) {
  int u = blockIdx.x;
  int lane = threadIdx.x;
  float csum = 0.f;
#pragma unroll
  for (int k = 0; k < 2; ++k) {
    int f = lane + k * 64;
    int idx = u * F_N + f;
    float sa = semi[idx];
    float s  = shift[idx];
    float inv = 1.0f / (sa * sa);
    A[idx]  = inv;
    B2[idx] = 2.0f * s * inv;
    csum += s * s * inv;
  }
#pragma unroll
  for (int off = 32; off > 0; off >>= 1)
    csum += __shfl_down(csum, off, 64);
  if (lane == 0) C[u] = csum;
}

__global__ __launch_bounds__(256) void main_kernel(
    const float* __restrict__ x,
    const float* __restrict__ A, const float* __restrict__ B2,
    const float* __restrict__ C, const float* __restrict__ sharp,
    const float* __restrict__ mult, float* __restrict__ out) {
  const int lane = threadIdx.x & 63;
  const int w    = threadIdx.x >> 6;
  const int b    = blockIdx.x * 256 + w * 64 + lane;  // one b-row per lane
  const int u0   = blockIdx.y * UB;

  float accA[UB], accB[UB];
#pragma unroll
  for (int u = 0; u < UB; ++u) { accA[u] = 0.f; accB[u] = 0.f; }

  const float4* xr = reinterpret_cast<const float4*>(x + (size_t)b * F_N);

  for (int c = 0; c < 4; ++c) {           // 4 chunks of 32 f's
    float xs[32], x2s[32];
#pragma unroll
    for (int q = 0; q < 8; ++q) {
      float4 v = xr[c * 8 + q];
      xs[q*4+0] = v.x; xs[q*4+1] = v.y; xs[q*4+2] = v.z; xs[q*4+3] = v.w;
    }
#pragma unroll
    for (int i = 0; i < 32; ++i) x2s[i] = xs[i] * xs[i];

#pragma unroll
    for (int u = 0; u < UB; ++u) {
      // wave-uniform addresses -> scalar loads (off the VALU pipe)
      const float4* Ar = reinterpret_cast<const float4*>(A  + (u0 + u) * F_N + c * 32);
      const float4* Br = reinterpret_cast<const float4*>(B2 + (u0 + u) * F_N + c * 32);
      float a0 = accA[u], a1 = accB[u];   // two independent chains for ILP
#pragma unroll
      for (int q = 0; q < 8; ++q) {
        float4 av = Ar[q];
        float4 bv = Br[q];
        a0 = fmaf(x2s[q*4+0], av.x, a0);  a1 = fmaf(xs[q*4+0], bv.x, a1);
        a0 = fmaf(x2s[q*4+1], av.y, a0);  a1 = fmaf(xs[q*4+1], bv.y, a1);
        a0 = fmaf(x2s[q*4+2], av.z, a0);  a1 = fmaf(xs[q*4+2], bv.z, a1);
        a0 = fmaf(x2s[q*4+3], av.w, a0);  a1 = fmaf(xs[q*4+3], bv.w, a1);
      }
      accA[u] = a0; accB[u] = a1;
    }
  }

  float res[UB];
#pragma unroll
  for (int u = 0; u < UB; ++u) {
    float quad = accA[u] + accB[u] + C[u0 + u];
    float z = sharp[u0 + u] * (1.0f - quad);
    float e = __expf(-z);                 // saturates to inf for huge -z -> sigmoid 0
    res[u] = mult[u0 + u] / (1.0f + e);
  }
  float4* o = reinterpret_cast<float4*>(out + (size_t)b * U_N + u0);
#pragma unroll
  for (int q = 0; q < UB / 4; ++q)
    o[q] = make_float4(res[q*4+0], res[q*4+1], res[q*4+2], res[q*4+3]);
}

extern "C" void kernel_launch(void* const* d_in, const int* in_sizes, int n_in,
                              void* d_out, int out_size, void* d_ws, size_t ws_size,
                              hipStream_t stream) {
  (void)in_sizes; (void)n_in; (void)out_size; (void)ws_size;
  const float* x     = (const float*)d_in[0];
  const float* shift = (const float*)d_in[1];
  const float* semi  = (const float*)d_in[2];
  const float* sharp = (const float*)d_in[3];
  const float* mult  = (const float*)d_in[4];
  float* out = (float*)d_out;

  float* A  = (float*)d_ws;              // U*F floats
  float* B2 = A + U_N * F_N;             // U*F floats
  float* C  = B2 + U_N * F_N;            // U floats  (total ~257 KB of d_ws)

  prep_kernel<<<U_N, 64, 0, stream>>>(shift, semi, A, B2, C);
  main_kernel<<<dim3(B_N / 256, U_N / UB), 256, 0, stream>>>(x, A, B2, C, sharp, mult, out);
}

// Round 2
// 20.246 us; speedup vs baseline: 4.7518x; 4.7518x over previous
//
#include <hip/hip_runtime.h>
#include <math.h>

#define B_N 8192
#define U_N 256
#define F_N 128
#define K_N 256          // concatenated K = 2*F
#define BTILE 16         // b-rows per block
#define NWAVE 8          // waves per block; wave w -> u-range [w*32, w*32+32)

typedef __attribute__((ext_vector_type(8))) short short8;   // 8 bf16 (4 VGPR)
typedef __attribute__((ext_vector_type(4))) float f32x4;    // MFMA C/D

static __device__ __forceinline__ unsigned short f2bf(float v) {
  union { float f; unsigned int u; } c; c.f = v;
  unsigned int r = c.u + 0x7fffu + ((c.u >> 16) & 1u);  // RNE
  return (unsigned short)(r >> 16);
}

// W[u][k] (ushort bf16): k<128 -> 1/sa^2 ; k>=128 -> 2*s/sa^2.  C[u] = sum s^2/sa^2 (f32)
__global__ __launch_bounds__(64) void prep_kernel(
    const float* __restrict__ shift, const float* __restrict__ semi,
    unsigned short* __restrict__ W, float* __restrict__ C) {
  int u = blockIdx.x;
  int lane = threadIdx.x;
  float csum = 0.f;
#pragma unroll
  for (int k = 0; k < 2; ++k) {
    int f = lane + k * 64;
    int idx = u * F_N + f;
    float sa = semi[idx];
    float s  = shift[idx];
    float inv = 1.0f / (sa * sa);
    W[u * K_N + f]        = f2bf(inv);
    W[u * K_N + F_N + f]  = f2bf(2.0f * s * inv);
    csum += s * s * inv;
  }
#pragma unroll
  for (int off = 32; off > 0; off >>= 1)
    csum += __shfl_down(csum, off, 64);
  if (lane == 0) C[u] = csum;
}

// out[b,u] = mult[u]/(1+exp(-sharp[u]*(1 - (G[b,:]·W[u,:] + C[u]))))
// G[b,k] = bf16(x^2) for k<128, bf16(x) for k>=128, staged in LDS (XOR-swizzled).
__global__ __launch_bounds__(512) void main_kernel(
    const float* __restrict__ x,
    const unsigned short* __restrict__ W, const float* __restrict__ C,
    const float* __restrict__ sharp, const float* __restrict__ mult,
    float* __restrict__ out) {
  __shared__ __align__(16) char Gs[BTILE * K_N * 2];   // 16 rows x 512 B = 8 KB

  const int tid  = threadIdx.x;
  const int lane = tid & 63;
  const int w    = tid >> 6;          // wave id 0..7
  const int b0   = blockIdx.x * BTILE;

  // ---- stage G: 16 rows x 128 f32 -> bf16(x^2) | bf16(x), swizzled ----
  {
    int row  = tid >> 5;              // 0..15
    int col4 = tid & 31;              // 0..31, covers f = col4*4..+3
    const float4 v = *reinterpret_cast<const float4*>(x + (size_t)(b0 + row) * F_N + col4 * 4);
    unsigned short q0[4], q1[4];
    float xs[4] = {v.x, v.y, v.z, v.w};
#pragma unroll
    for (int j = 0; j < 4; ++j) { q0[j] = f2bf(xs[j] * xs[j]); q1[j] = f2bf(xs[j]); }
    int sw = (row & 7) << 4;          // XOR swizzle on byte bits 4..6
    int byte0 = row * 512 + ((col4 * 8)       ^ sw);
    int byte1 = row * 512 + ((256 + col4 * 8) ^ sw);
    *reinterpret_cast<uint2*>(&Gs[byte0]) = *reinterpret_cast<uint2*>(q0);
    *reinterpret_cast<uint2*>(&Gs[byte1]) = *reinterpret_cast<uint2*>(q1);
  }
  __syncthreads();

  // ---- GEMM: wave w owns u-tile [w*32, w*32+32) = 2 subtiles of 16 ----
  const int n0 = w * 32;
  const int lg = lane >> 4;           // 0..3 (k-group)
  const int ln = lane & 15;           // n/m within tile

  f32x4 acc0 = {0.f, 0.f, 0.f, 0.f};
  f32x4 acc1 = {0.f, 0.f, 0.f, 0.f};

  const int arow = ln;                // m within b-tile
  const int asw  = (arow & 7) << 4;

#pragma unroll
  for (int kk = 0; kk < 8; ++kk) {    // k0 = kk*32
    int kbyte = kk * 64 + lg * 16;
    short8 a = *reinterpret_cast<const short8*>(&Gs[arow * 512 + (kbyte ^ asw)]);
    const unsigned short* wp0 = W + (size_t)(n0 + ln) * K_N + kk * 32 + lg * 8;
    const unsigned short* wp1 = wp0 + 16 * K_N;
    short8 bfr0 = *reinterpret_cast<const short8*>(wp0);
    short8 bfr1 = *reinterpret_cast<const short8*>(wp1);
    acc0 = __builtin_amdgcn_mfma_f32_16x16x32_bf16(a, bfr0, acc0, 0, 0, 0);
    acc1 = __builtin_amdgcn_mfma_f32_16x16x32_bf16(a, bfr1, acc1, 0, 0, 0);
  }

  // ---- fused epilogue: sigmoid, scatter-store f32 ----
#pragma unroll
  for (int s = 0; s < 2; ++s) {
    f32x4 acc = s ? acc1 : acc0;
    int u = n0 + s * 16 + ln;
    float c  = C[u];
    float sh = sharp[u];
    float mu = mult[u];
#pragma unroll
    for (int r = 0; r < 4; ++r) {
      int b = b0 + lg * 4 + r;
      float quad = acc[r] + c;
      float z = sh * (1.0f - quad);
      float e = __expf(-z);           // inf for saturated -> result ±0
      out[(size_t)b * U_N + u] = mu / (1.0f + e);
    }
  }
}

extern "C" void kernel_launch(void* const* d_in, const int* in_sizes, int n_in,
                              void* d_out, int out_size, void* d_ws, size_t ws_size,
                              hipStream_t stream) {
  (void)in_sizes; (void)n_in; (void)out_size; (void)ws_size;
  const float* x     = (const float*)d_in[0];
  const float* shift = (const float*)d_in[1];
  const float* semi  = (const float*)d_in[2];
  const float* sharp = (const float*)d_in[3];
  const float* mult  = (const float*)d_in[4];
  float* out = (float*)d_out;

  unsigned short* W = (unsigned short*)d_ws;            // 256*256 bf16 = 128 KB
  float* C = (float*)((char*)d_ws + U_N * K_N * sizeof(unsigned short)); // 1 KB

  prep_kernel<<<U_N, 64, 0, stream>>>(shift, semi, W, C);
  main_kernel<<<B_N / BTILE, 512, 0, stream>>>(x, W, C, sharp, mult, out);
}

// Round 3
// 13.022 us; speedup vs baseline: 7.3880x; 1.5548x over previous
//
#include <hip/hip_runtime.h>
#include <math.h>

#define B_N 8192
#define U_N 256
#define F_N 128
#define UG  32    // u's per block = 2 MFMA n-tiles
#define BT  128   // b-rows per block = 8 waves x 16

typedef __attribute__((ext_vector_type(8))) short short8;   // 8 bf16
typedef __attribute__((ext_vector_type(4))) float f32x4;    // MFMA C/D

static __device__ __forceinline__ unsigned short f2bf(float v) {
  union { float f; unsigned int u; } c; c.f = v;
  unsigned int r = c.u + 0x7fffu + ((c.u >> 16) & 1u);  // RNE
  return (unsigned short)(r >> 16);
}

// One fused kernel. Block = (b-tile of 128 rows) x (u-group of 32 units).
// Phase 1: build W fragments for this u-group in LDS (MFMA-ready layout) + C sums.
// Phase 2: each wave computes 16 b-rows x 32 u's via 16 MFMAs, A-operand in regs.
__global__ __launch_bounds__(512, 4) void bp_kernel(
    const float* __restrict__ x, const float* __restrict__ shift,
    const float* __restrict__ semi, const float* __restrict__ sharp,
    const float* __restrict__ mult, float* __restrict__ out) {
  // Wf[tile][kk][lane][j] = W[u0 + tile*16 + (lane&15)][kk*32 + (lane>>4)*8 + j]
  // where W[u][k] = (k<128) ? 1/sa^2 : 2*s/sa^2
  __shared__ __align__(16) unsigned short Wf[2][8][64][8];  // 16 KB
  __shared__ float Cs[UG];                                  // 128 B

  const int tid   = threadIdx.x;
  const int lane  = tid & 63;
  const int w     = tid >> 6;
  const int lg    = lane >> 4;   // 0..3 (k-group / acc row group)
  const int ln    = lane & 15;   // 0..15 (m row for A, n col for B)
  const int btile = blockIdx.x;  // 0..63
  const int u0    = blockIdx.y * UG;

  // ---- issue x loads early (independent of prep) ----
  const int brow0 = btile * BT + w * 16;
  const float* xrow = x + (size_t)(brow0 + ln) * F_N;
  float4 xv[8];
#pragma unroll
  for (int s4 = 0; s4 < 4; ++s4) {
    xv[s4 * 2]     = *reinterpret_cast<const float4*>(xrow + s4 * 32 + lg * 8);
    xv[s4 * 2 + 1] = *reinterpret_cast<const float4*>(xrow + s4 * 32 + lg * 8 + 4);
  }

  // ---- phase 1: prep W fragments + C for this block's 32 u's ----
  {
    const int u_loc = tid >> 4;         // 0..31
    const int f0    = (tid & 15) * 8;   // 0..120, 8-aligned
    const float* sp = shift + (size_t)(u0 + u_loc) * F_N + f0;
    const float* ap = semi  + (size_t)(u0 + u_loc) * F_N + f0;
    float4 s0 = *reinterpret_cast<const float4*>(sp);
    float4 s1 = *reinterpret_cast<const float4*>(sp + 4);
    float4 a0 = *reinterpret_cast<const float4*>(ap);
    float4 a1 = *reinterpret_cast<const float4*>(ap + 4);
    float ss[8] = {s0.x, s0.y, s0.z, s0.w, s1.x, s1.y, s1.z, s1.w};
    float aa[8] = {a0.x, a0.y, a0.z, a0.w, a1.x, a1.y, a1.z, a1.w};
    unsigned short qi[8], qb[8];
    float csum = 0.f;
#pragma unroll
    for (int j = 0; j < 8; ++j) {
      float inv = 1.0f / (aa[j] * aa[j]);
      qi[j] = f2bf(inv);
      qb[j] = f2bf(2.0f * ss[j] * inv);
      csum += ss[j] * ss[j] * inv;
    }
    const int tile = u_loc >> 4;
    const int kkp  = f0 >> 5;                       // 0..3
    const int lnp  = ((f0 >> 3) & 3) * 16 + (u_loc & 15);  // fragment lane
    *reinterpret_cast<uint2*>(&Wf[tile][kkp][lnp][0])     = *reinterpret_cast<uint2*>(qi);
    *reinterpret_cast<uint2*>(&Wf[tile][kkp][lnp][4])     = *reinterpret_cast<uint2*>(qi + 4);
    *reinterpret_cast<uint2*>(&Wf[tile][kkp + 4][lnp][0]) = *reinterpret_cast<uint2*>(qb);
    *reinterpret_cast<uint2*>(&Wf[tile][kkp + 4][lnp][4]) = *reinterpret_cast<uint2*>(qb + 4);
    // reduce csum across the 16 threads sharing u_loc (lane bits 0..3)
    csum += __shfl_xor(csum, 1, 64);
    csum += __shfl_xor(csum, 2, 64);
    csum += __shfl_xor(csum, 4, 64);
    csum += __shfl_xor(csum, 8, 64);
    if ((lane & 15) == 0) Cs[u_loc] = csum;
  }

  // ---- convert A fragments while prep finishes elsewhere ----
  short8 fx2[4], fx1[4];
#pragma unroll
  for (int s4 = 0; s4 < 4; ++s4) {
    float xs[8] = {xv[s4*2].x, xv[s4*2].y, xv[s4*2].z, xv[s4*2].w,
                   xv[s4*2+1].x, xv[s4*2+1].y, xv[s4*2+1].z, xv[s4*2+1].w};
    short8 a2, a1;
#pragma unroll
    for (int j = 0; j < 8; ++j) {
      a2[j] = (short)f2bf(xs[j] * xs[j]);
      a1[j] = (short)f2bf(xs[j]);
    }
    fx2[s4] = a2; fx1[s4] = a1;
  }

  __syncthreads();

  // ---- phase 2: GEMM, K = 256 (k<128: x^2 * inv ; k>=128: x * 2 s inv) ----
  f32x4 acc0 = {0.f, 0.f, 0.f, 0.f};
  f32x4 acc1 = {0.f, 0.f, 0.f, 0.f};
#pragma unroll
  for (int kk = 0; kk < 8; ++kk) {
    short8 a = (kk < 4) ? fx2[kk] : fx1[kk - 4];
    short8 b0 = *reinterpret_cast<const short8*>(&Wf[0][kk][lane][0]);
    short8 b1 = *reinterpret_cast<const short8*>(&Wf[1][kk][lane][0]);
    acc0 = __builtin_amdgcn_mfma_f32_16x16x32_bf16(a, b0, acc0, 0, 0, 0);
    acc1 = __builtin_amdgcn_mfma_f32_16x16x32_bf16(a, b1, acc1, 0, 0, 0);
  }

  // ---- epilogue: quad + C, sigmoid, scale, store ----
#pragma unroll
  for (int s = 0; s < 2; ++s) {
    f32x4 acc = s ? acc1 : acc0;
    const int u = u0 + s * 16 + ln;
    const float c  = Cs[s * 16 + ln];
    const float sh = sharp[u];
    const float mu = mult[u];
#pragma unroll
    for (int r = 0; r < 4; ++r) {
      const int b = brow0 + lg * 4 + r;
      float quad = acc[r] + c;
      float z = sh * (1.0f - quad);
      float e = __expf(-z);            // inf when saturated -> result ±0
      out[(size_t)b * U_N + u] = mu / (1.0f + e);
    }
  }
}

extern "C" void kernel_launch(void* const* d_in, const int* in_sizes, int n_in,
                              void* d_out, int out_size, void* d_ws, size_t ws_size,
                              hipStream_t stream) {
  (void)in_sizes; (void)n_in; (void)out_size; (void)d_ws; (void)ws_size;
  const float* x     = (const float*)d_in[0];
  const float* shift = (const float*)d_in[1];
  const float* semi  = (const float*)d_in[2];
  const float* sharp = (const float*)d_in[3];
  const float* mult  = (const float*)d_in[4];
  float* out = (float*)d_out;

  bp_kernel<<<dim3(B_N / BT, U_N / UG), 512, 0, stream>>>(x, shift, semi, sharp, mult, out);
}